// Round 8
// baseline (103.291 us; speedup 1.0000x reference)
//
#include <hip/hip_runtime.h>

#define NB 8
#define NA 9
#define NCELL (128 * 128)    // 16384
#define NTOT (NCELL * NA)    // 147456
#define PRE_K 2000
#define POST_K 300
#define CAP2 8192            // coarse candidate cap per batch
#define PARTS 18             // sweep blocks per batch (1024 thr, 8192 elems each)
#define NMS_TH 0.7f

// anchor widths/heights (exact integers); all anchor centers are 16*(w,h)+8
__constant__ float c_aw[NA] = {184.f, 368.f, 736.f, 128.f, 256.f, 512.f, 88.f, 176.f, 352.f};
__constant__ float c_ah[NA] = {96.f, 192.f, 384.f, 128.f, 256.f, 512.f, 176.f, 352.f, 704.f};

__device__ __forceinline__ unsigned int sortable(float s) {
    unsigned int u = __float_as_uint(s);
    return (u & 0x80000000u) ? ~u : (u | 0x80000000u);
}

__device__ __forceinline__ unsigned long long shflx64(unsigned long long v, int m) {
    return __shfl_xor(v, m, 64);
}

// ---------- pass 0: 11-bit LDS histogram, per-block write-out ----------
// grid (PARTS, NB) x 1024; block covers 2048 float4 = 8192 elems
__global__ __launch_bounds__(1024) void hist0_kernel(const float* __restrict__ scores,
                                                     unsigned int* __restrict__ h0out) {
    __shared__ unsigned int h[2048];
    int b = blockIdx.y, tid = threadIdx.x;
    h[tid] = 0; h[tid + 1024] = 0;
    __syncthreads();
    const float4* sp4 = (const float4*)(scores + (size_t)b * 18 * NCELL + (size_t)NA * NCELL);
    int base4 = blockIdx.x * 2048;
#pragma unroll
    for (int e = 0; e < 2; ++e) {
        float4 v = sp4[base4 + e * 1024 + tid];
        atomicAdd(&h[sortable(v.x) >> 21], 1u);
        atomicAdd(&h[sortable(v.y) >> 21], 1u);
        atomicAdd(&h[sortable(v.z) >> 21], 1u);
        atomicAdd(&h[sortable(v.w) >> 21], 1u);
    }
    __syncthreads();
    unsigned int* o = h0out + ((size_t)(b * PARTS + blockIdx.x)) * 2048;
    o[tid] = h[tid];
    o[tid + 1024] = h[tid + 1024];
}

// ---------- select over 2048 bins (wave-level suffix scan); zero gh1 + cnt ----------
__global__ __launch_bounds__(1024) void select0_kernel(const unsigned int* __restrict__ h0out,
                                                       uint2* __restrict__ state0,
                                                       unsigned int* __restrict__ gh1,
                                                       int* __restrict__ cnt) {
    __shared__ unsigned int wpart[16], wexcl[16];
    __shared__ unsigned int thr[1024];
    int b = blockIdx.x, tid = threadIdx.x;
    int lane = tid & 63, wid = tid >> 6;
    if (tid < 128) gh1[b * 128 + tid] = 0;
    if (tid == 0) cnt[b] = 0;
    unsigned int c0 = 0, c1 = 0;
    for (int p = 0; p < PARTS; ++p) {
        const unsigned int* hp = h0out + ((size_t)(b * PARTS + p)) * 2048;
        uint2 v = *(const uint2*)&hp[2 * tid];
        c0 += v.x; c1 += v.y;
    }
    // in-wave inclusive suffix scan
    unsigned int sum = c0 + c1;
#pragma unroll
    for (int off = 1; off < 64; off <<= 1) {
        unsigned int v = __shfl_down(sum, off, 64);
        if (lane + off < 64) sum += v;
    }
    if (lane == 0) wpart[wid] = sum;
    __syncthreads();
    if (tid < 16) {
        unsigned int e = 0;
        for (int w = tid + 1; w < 16; ++w) e += wpart[w];
        wexcl[tid] = e;
    }
    __syncthreads();
    unsigned int self = sum + wexcl[wid];    // count(bins >= 2*tid)
    thr[tid] = self;
    __syncthreads();
    unsigned int above = (tid < 1023) ? thr[tid + 1] : 0u;  // count(bins >= 2*tid+2)
    if (self >= (unsigned)PRE_K && above < (unsigned)PRE_K) {
        if (above + c1 >= (unsigned)PRE_K)
            state0[b] = make_uint2((unsigned)(2 * tid + 1), (unsigned)(PRE_K)-above);
        else
            state0[b] = make_uint2((unsigned)(2 * tid), (unsigned)(PRE_K)-above - c1);
    }
}

// ---------- gather at coarse 11-bit pivot + 128-bin refinement hist ----------
// grid (PARTS, NB) x 1024
__global__ __launch_bounds__(1024) void gatherc_kernel(const float* __restrict__ scores,
                                                       const uint2* __restrict__ state0,
                                                       unsigned int* __restrict__ gh1,
                                                       int* __restrict__ cnt,
                                                       unsigned long long* __restrict__ buf) {
    __shared__ unsigned long long lbuf[2048];
    __shared__ unsigned int h128[128];
    __shared__ int lmisc[2];   // [0]=lcnt [1]=gbase
    int b = blockIdx.y, tid = threadIdx.x;
    if (tid < 128) h128[tid] = 0;
    if (tid == 0) lmisc[0] = 0;
    __syncthreads();
    unsigned int piv = state0[b].x;
    unsigned int P = piv << 21;          // coarse threshold (floor of pivot bin)
    const float4* sp4 = (const float4*)(scores + (size_t)b * 18 * NCELL + (size_t)NA * NCELL);
    int base4 = blockIdx.x * 2048;
#pragma unroll
    for (int e = 0; e < 2; ++e) {
        int t4 = base4 + e * 1024 + tid;
        float4 v = sp4[t4];
        float el[4] = {v.x, v.y, v.z, v.w};
#pragma unroll
        for (int j = 0; j < 4; ++j) {
            unsigned int u = sortable(el[j]);
            if (u >= P) {
                if ((u >> 21) == piv) atomicAdd(&h128[(u >> 14) & 127u], 1u);
                int idx4 = t4 * 4 + j;            // = a*16384 + cell (channel-major)
                int a = idx4 >> 14;
                int cell = idx4 & 16383;
                unsigned int i = (unsigned int)cell * 9u + (unsigned int)a;
                int pos = atomicAdd(&lmisc[0], 1);
                if (pos < 2048)
                    lbuf[pos] = ((unsigned long long)u << 32) |
                                (unsigned long long)(0xFFFFFFFFu - i);
            }
        }
    }
    __syncthreads();
    if (tid < 128 && h128[tid]) atomicAdd(&gh1[b * 128 + tid], h128[tid]);
    if (tid == 0) lmisc[1] = atomicAdd(&cnt[b], min(lmisc[0], 2048));
    __syncthreads();
    int m = min(lmisc[0], 2048), gb = lmisc[1];
    for (int t = tid; t < m; t += 1024) {
        int g = gb + t;
        if (g < CAP2) buf[(size_t)b * CAP2 + g] = lbuf[t];
    }
}

// ---------- per-batch: exact pivot + filter + hybrid sort + inline decode ----------
#define SHFL_STEP(J)                                                          \
    {                                                                         \
        int d_ = (J) >> 1;                                                    \
        bool keepMax = (((tid & d_) == 0) == (((2u * (unsigned)tid) & k) == 0)); \
        unsigned long long pa = shflx64(va, d_);                              \
        unsigned long long pb = shflx64(vb, d_);                              \
        va = keepMax ? (va > pa ? va : pa) : (va < pa ? va : pa);             \
        vb = keepMax ? (vb > pb ? vb : pb) : (vb < pb ? vb : pb);             \
    }
#define LOCAL_STEP()                                                          \
    {                                                                         \
        bool desc = (((2u * (unsigned)tid) & k) == 0);                        \
        unsigned long long lo = va < vb ? va : vb;                            \
        unsigned long long hi = va < vb ? vb : va;                            \
        va = desc ? hi : lo; vb = desc ? lo : hi;                             \
    }

__global__ __launch_bounds__(1024) void sortdec_kernel(const unsigned long long* __restrict__ buf,
                                                       const int* __restrict__ cnt,
                                                       const uint2* __restrict__ state0,
                                                       const unsigned int* __restrict__ gh1,
                                                       const float* __restrict__ deltas,
                                                       const float* __restrict__ im_info,
                                                       float4* __restrict__ props) {
    __shared__ unsigned long long s[4096];
    __shared__ unsigned int spiv;
    __shared__ int fcnt;
    int b = blockIdx.x, tid = threadIdx.x;
    if (tid == 0) fcnt = 0;
    // exact 18-bit pivot from refinement hist (wave 0)
    if (tid < 64) {
        int lane = tid;
        unsigned int c0 = gh1[b * 128 + 2 * lane];
        unsigned int c1 = gh1[b * 128 + 2 * lane + 1];
        unsigned int sum = c0 + c1;
#pragma unroll
        for (int off = 1; off < 64; off <<= 1) {
            unsigned int v = __shfl_down(sum, off, 64);
            if (lane + off < 64) sum += v;
        }
        unsigned int above = __shfl_down(sum, 1, 64);
        if (lane == 63) above = 0;
        unsigned int need0 = state0[b].y;
        if (sum >= need0 && above < need0) {
            unsigned int d = (above + c1 >= need0) ? (unsigned)(2 * lane + 1) : (unsigned)(2 * lane);
            spiv = ((state0[b].x << 7) | d) << 14;
        }
    }
    __syncthreads();
    unsigned int P = spiv;
    int n = min(cnt[b], CAP2);
    const unsigned long long* src = buf + (size_t)b * CAP2;
    for (int t = tid; t < n; t += 1024) {
        unsigned long long e = src[t];
        if ((unsigned int)(e >> 32) >= P) {
            int pos = atomicAdd(&fcnt, 1);
            if (pos < 4096) s[pos] = e;
        }
    }
    __syncthreads();
    int n2 = min(fcnt, 4096);
    int SZ = (n2 <= 2048) ? 2048 : 4096;
    for (int t = tid; t < SZ; t += 1024)
        if (t >= n2) s[t] = 0ULL;
    __syncthreads();
    if (SZ == 2048) {
        unsigned long long va = s[2 * tid], vb = s[2 * tid + 1];
#pragma unroll
        for (unsigned k = 2; k <= 128; k <<= 1) {
#pragma unroll
            for (unsigned j = k >> 1; j >= 2; j >>= 1) SHFL_STEP(j)
            LOCAL_STEP()
        }
        for (unsigned k = 256; k <= 2048; k <<= 1) {
            s[2 * tid] = va; s[2 * tid + 1] = vb;
            __syncthreads();
            for (unsigned j = k >> 1; j >= 128; j >>= 1) {
                for (int t = tid; t < 2048; t += 1024) {
                    int ixj = t ^ (int)j;
                    if (ixj > t) {
                        unsigned long long x = s[t], y = s[ixj];
                        if ((((unsigned)t & k) == 0) ? (x < y) : (x > y)) { s[t] = y; s[ixj] = x; }
                    }
                }
                __syncthreads();
            }
            va = s[2 * tid]; vb = s[2 * tid + 1];
#pragma unroll
            for (unsigned j = 64; j >= 2; j >>= 1) SHFL_STEP(j)
            LOCAL_STEP()
        }
        s[2 * tid] = va; s[2 * tid + 1] = vb;
        __syncthreads();
    } else {
        for (int k = 2; k <= 4096; k <<= 1) {
            for (int j = k >> 1; j > 0; j >>= 1) {
                for (int t = tid; t < 4096; t += 1024) {
                    int ixj = t ^ j;
                    if (ixj > t) {
                        unsigned long long x = s[t], y = s[ixj];
                        if (((t & k) == 0) ? (x < y) : (x > y)) { s[t] = y; s[ixj] = x; }
                    }
                }
                __syncthreads();
            }
        }
    }
    // inline decode + clip (numerics identical to passing version)
    float maxx = __fsub_rn(im_info[b * 3 + 1], 1.0f);
    float maxy = __fsub_rn(im_info[b * 3 + 0], 1.0f);
    const float* dbase = deltas + (size_t)b * 36 * NCELL;
    for (int r = tid; r < PRE_K; r += 1024) {
        unsigned int i = 0xFFFFFFFFu - (unsigned int)(s[r] & 0xFFFFFFFFu);
        unsigned int cell = i / 9u;
        unsigned int a = i - cell * 9u;
        int wx = (int)(cell & 127u), hy = (int)(cell >> 7);
        const float* dp = dbase + (size_t)(4u * a) * NCELL + (size_t)hy * 128 + wx;
        float dx = dp[0];
        float dy = dp[NCELL];
        float dw = dp[2 * NCELL];
        float dh = dp[3 * NCELL];
        float W_ = c_aw[a], H_ = c_ah[a];
        float cx = (float)(16 * wx + 8), cy = (float)(16 * hy + 8);
        float px = __fadd_rn(__fmul_rn(dx, W_), cx);
        float py = __fadd_rn(__fmul_rn(dy, H_), cy);
        float pw = __fmul_rn((float)exp((double)dw), W_);
        float ph = __fmul_rn((float)exp((double)dh), H_);
        float hw = __fmul_rn(0.5f, pw), hh = __fmul_rn(0.5f, ph);
        float x1 = __fsub_rn(px, hw), y1 = __fsub_rn(py, hh);
        float x2 = __fadd_rn(px, hw), y2 = __fadd_rn(py, hh);
        x1 = fminf(fmaxf(x1, 0.0f), maxx);
        y1 = fminf(fmaxf(y1, 0.0f), maxy);
        x2 = fminf(fmaxf(x2, 0.0f), maxx);
        y2 = fminf(fmaxf(y2, 0.0f), maxy);
        props[(size_t)b * PRE_K + r] = make_float4(x1, y1, x2, y2);
    }
}

// ---------------- NMS suppression bitmask, COLUMN form, word-major ----------------
// colm[(b*32 + iT)*2048 + j] : bit ii set iff box i=iT*64+ii suppresses box j (i<j, iou>th)
// grid (32 iTiles, 32 jTiles, B), block 64
__global__ void mask_kernel(const float4* __restrict__ boxes,
                            unsigned long long* __restrict__ colm) {
    int iT = blockIdx.x, jT = blockIdx.y, b = blockIdx.z;
    if (iT > jT) return;
    __shared__ float4 ib[64];
    int t = threadIdx.x;
    int i0 = iT * 64;
    ib[t] = (i0 + t < PRE_K) ? boxes[(size_t)b * PRE_K + i0 + t] : make_float4(0.f, 0.f, -1.f, -1.f);
    __syncthreads();
    int j = jT * 64 + t;
    if (j >= PRE_K) return;
    float4 jb = boxes[(size_t)b * PRE_K + j];
    float barea = __fmul_rn(__fsub_rn(jb.z, jb.x), __fsub_rn(jb.w, jb.y));
    unsigned long long m = 0ULL;
    for (int ii = 0; ii < 64; ++ii) {
        int i = i0 + ii;
        if (i < j) {   // i < j < PRE_K
            float4 c = ib[ii];
            float aarea = __fmul_rn(__fsub_rn(c.z, c.x), __fsub_rn(c.w, c.y));
            float xx1 = fmaxf(c.x, jb.x), yy1 = fmaxf(c.y, jb.y);
            float xx2 = fminf(c.z, jb.z), yy2 = fminf(c.w, jb.w);
            float iw = fmaxf(__fsub_rn(xx2, xx1), 0.0f);
            float ih = fmaxf(__fsub_rn(yy2, yy1), 0.0f);
            float inter = __fmul_rn(iw, ih);
            float denom = __fadd_rn(__fsub_rn(__fadd_rn(aarea, barea), inter), 1e-9f);
            float iou = __fdiv_rn(inter, denom);
            if (iou > NMS_TH) m |= (1ULL << ii);
        }
    }
    colm[((size_t)b * 32 + iT) * 2048 + j] = m;
}

// ---------------- greedy scan via ballots, one wave per batch ----------------
__global__ void scan_kernel(const unsigned long long* __restrict__ colm,
                            const float4* __restrict__ boxes,
                            float* __restrict__ out) {
    int b = blockIdx.x;
    int lane = threadIdx.x;  // 64 threads = 1 wave
    __shared__ unsigned long long kw[32];
    __shared__ int keeplist[POST_K];
    const unsigned long long* cb = colm + (size_t)b * 32 * 2048;
    int total = 0;
    bool done = false;
    for (int k = 0; k < 32 && !done; ++k) {
        int j = k * 64 + lane;
        // dead_j = suppressed by any earlier KEPT box (coalesced loads, 4-way ILP)
        unsigned long long d = 0;
        int w = 0;
        for (; w + 4 <= k; w += 4) {
            unsigned long long a0 = cb[(size_t)(w + 0) * 2048 + j] & kw[w + 0];
            unsigned long long a1 = cb[(size_t)(w + 1) * 2048 + j] & kw[w + 1];
            unsigned long long a2 = cb[(size_t)(w + 2) * 2048 + j] & kw[w + 2];
            unsigned long long a3 = cb[(size_t)(w + 3) * 2048 + j] & kw[w + 3];
            d |= (a0 | a1) | (a2 | a3);
        }
        for (; w < k; ++w) d |= cb[(size_t)w * 2048 + j] & kw[w];
        unsigned long long diag = cb[(size_t)k * 2048 + j];
        bool alive_me = (d == 0ULL) && (j < PRE_K);
        unsigned long long alive = __ballot(alive_me);
        unsigned long long keptw = 0ULL;
        while (alive) {
            int i = __builtin_ctzll(alive);
            keptw |= (1ULL << i);
            if (lane == 0 && total < POST_K) keeplist[total] = k * 64 + i;
            total++;
            if (total >= POST_K) { done = true; break; }
            unsigned long long sup = __ballot(((diag >> i) & 1ULL) != 0ULL);
            alive &= ~sup;
            alive &= ~keptw;
        }
        if (lane == 0) kw[k] = keptw;
        __syncthreads();
    }
    __syncthreads();
    int K = min(total, POST_K);
    const float4* bb = boxes + (size_t)b * PRE_K;
    for (int r = lane; r < POST_K; r += 64) {
        float4 v = make_float4(0.f, 0.f, 0.f, 0.f);
        if (r < K) v = bb[keeplist[r]];
        float* o = out + ((size_t)b * POST_K + r) * 5;
        o[0] = (float)b;
        o[1] = v.x;
        o[2] = v.y;
        o[3] = v.z;
        o[4] = v.w;
    }
}

// ---------------- launcher ----------------
extern "C" void kernel_launch(void* const* d_in, const int* in_sizes, int n_in,
                              void* d_out, int out_size, void* d_ws, size_t ws_size,
                              hipStream_t stream) {
    const float* scores = (const float*)d_in[0];
    const float* deltas = (const float*)d_in[1];
    const float* im_info = (const float*)d_in[2];
    float* out = (float*)d_out;
    char* ws = (char*)d_ws;

    // workspace layout (bytes)
    unsigned int* h0out = (unsigned int*)(ws + 0);                 // 144*2048*4 = 1179648
    unsigned int* gh1 = (unsigned int*)(ws + 1179648);             // 4096
    uint2* state0 = (uint2*)(ws + 1183744);                        // 64
    int* cnt = (int*)(ws + 1183808);                               // 64
    unsigned long long* buf = (unsigned long long*)(ws + 1183872); // 8*8192*8 = 524288
    float4* props = (float4*)(ws + 1708160);                       // 8*2000*16 = 256000
    unsigned long long* colm = (unsigned long long*)(ws + 1966080);// 8*32*2048*8 = 4194304
    // total ≈ 6.16 MB; select0 zeroes gh1+cnt; everything else written before read

    hipLaunchKernelGGL(hist0_kernel, dim3(PARTS, NB), dim3(1024), 0, stream, scores, h0out);
    hipLaunchKernelGGL(select0_kernel, dim3(NB), dim3(1024), 0, stream, h0out, state0, gh1, cnt);
    hipLaunchKernelGGL(gatherc_kernel, dim3(PARTS, NB), dim3(1024), 0, stream,
                       scores, state0, gh1, cnt, buf);
    hipLaunchKernelGGL(sortdec_kernel, dim3(NB), dim3(1024), 0, stream,
                       buf, cnt, state0, gh1, deltas, im_info, props);
    hipLaunchKernelGGL(mask_kernel, dim3(32, 32, NB), dim3(64), 0, stream, props, colm);
    hipLaunchKernelGGL(scan_kernel, dim3(NB), dim3(64), 0, stream, colm, props, out);
}

// Round 9
// 102.256 us; speedup vs baseline: 1.0101x; 1.0101x over previous
//
#include <hip/hip_runtime.h>

#define NB 8
#define NA 9
#define NCELL (128 * 128)    // 16384
#define NTOT (NCELL * NA)    // 147456
#define PRE_K 2000
#define POST_K 300
#define PARTS 18             // sweep blocks per batch (1024 thr, 8192 elems each)
#define SLOT 512             // candidate slots per sweep block
#define THR_BIN 0x5FFu       // static gather bin: sortable(1.75f)>>21
#define NMS_TH 0.7f

// anchor widths/heights (exact integers); all anchor centers are 16*(w,h)+8
__constant__ float c_aw[NA] = {184.f, 368.f, 736.f, 128.f, 256.f, 512.f, 88.f, 176.f, 352.f};
__constant__ float c_ah[NA] = {96.f, 192.f, 384.f, 128.f, 256.f, 512.f, 176.f, 352.f, 704.f};

__device__ __forceinline__ unsigned int sortable(float s) {
    unsigned int u = __float_as_uint(s);
    return (u & 0x80000000u) ? ~u : (u | 0x80000000u);
}

__device__ __forceinline__ unsigned long long shflx64(unsigned long long v, int m) {
    return __shfl_xor(v, m, 64);
}

// ---------- single sweep: 2048-bin hist + static-threshold gather into slots ----------
// grid (PARTS, NB) x 1024; block covers 2048 float4 = 8192 elems
__global__ __launch_bounds__(1024) void sweep_kernel(const float* __restrict__ scores,
                                                     unsigned int* __restrict__ h0out,
                                                     int* __restrict__ bcnt,
                                                     unsigned long long* __restrict__ buf) {
    __shared__ unsigned int h[2048];
    __shared__ unsigned long long lbuf[SLOT];
    __shared__ int lcnt;
    int b = blockIdx.y, part = blockIdx.x, tid = threadIdx.x;
    h[tid] = 0; h[tid + 1024] = 0;
    if (tid == 0) lcnt = 0;
    __syncthreads();
    const float4* sp4 = (const float4*)(scores + (size_t)b * 18 * NCELL + (size_t)NA * NCELL);
    int base4 = part * 2048;
#pragma unroll
    for (int e = 0; e < 2; ++e) {
        int t4 = base4 + e * 1024 + tid;
        float4 v = sp4[t4];
        float el[4] = {v.x, v.y, v.z, v.w};
#pragma unroll
        for (int j = 0; j < 4; ++j) {
            unsigned int u = sortable(el[j]);
            atomicAdd(&h[u >> 21], 1u);
            if ((u >> 21) >= THR_BIN) {
                int idx4 = t4 * 4 + j;            // = a*16384 + cell (channel-major)
                int a = idx4 >> 14;
                int cell = idx4 & 16383;
                unsigned int i = (unsigned int)cell * 9u + (unsigned int)a;
                int pos = atomicAdd(&lcnt, 1);
                if (pos < SLOT)
                    lbuf[pos] = ((unsigned long long)u << 32) |
                                (unsigned long long)(0xFFFFFFFFu - i);
            }
        }
    }
    __syncthreads();
    unsigned int* o = h0out + ((size_t)(b * PARTS + part)) * 2048;
    o[tid] = h[tid];
    o[tid + 1024] = h[tid + 1024];
    if (tid == 0) bcnt[b * PARTS + part] = lcnt;   // raw count (may exceed SLOT)
    int m = min(lcnt, SLOT);
    for (int t = tid; t < m; t += 1024)
        buf[((size_t)(b * PARTS + part)) * SLOT + t] = lbuf[t];
}

// ---------- per-batch: coarse select + refine + filter + hybrid sort + decode ----------
#define SHFL_STEP(J)                                                          \
    {                                                                         \
        int d_ = (J) >> 1;                                                    \
        bool keepMax = (((tid & d_) == 0) == (((2u * (unsigned)tid) & k) == 0)); \
        unsigned long long pa = shflx64(va, d_);                              \
        unsigned long long pb = shflx64(vb, d_);                              \
        va = keepMax ? (va > pa ? va : pa) : (va < pa ? va : pa);             \
        vb = keepMax ? (vb > pb ? vb : pb) : (vb < pb ? vb : pb);             \
    }
#define LOCAL_STEP()                                                          \
    {                                                                         \
        bool desc = (((2u * (unsigned)tid) & k) == 0);                        \
        unsigned long long lo = va < vb ? va : vb;                            \
        unsigned long long hi = va < vb ? vb : va;                            \
        va = desc ? hi : lo; vb = desc ? lo : hi;                             \
    }

__global__ __launch_bounds__(1024) void sortdec_kernel(const float* __restrict__ scores,
                                                       const unsigned int* __restrict__ h0out,
                                                       const int* __restrict__ bcnt,
                                                       const unsigned long long* __restrict__ buf,
                                                       const float* __restrict__ deltas,
                                                       const float* __restrict__ im_info,
                                                       float4* __restrict__ props) {
    __shared__ unsigned long long s[4096];        // 32 KB; aliased as thr[] in phase A
    __shared__ unsigned int wpart[16], wexcl[16];
    __shared__ unsigned int h128[128];
    __shared__ int sbc[PARTS];
    __shared__ unsigned int sh_piv, sh_spiv;
    __shared__ unsigned int sh_need;
    __shared__ int sh_ok, fcnt;
    int b = blockIdx.x, tid = threadIdx.x;
    int lane = tid & 63, wid = tid >> 6;
    unsigned int* thr = (unsigned int*)s;   // phase-A only

    if (tid < PARTS) sbc[tid] = bcnt[b * PARTS + tid];
    if (tid == 0) { sh_ok = 1; fcnt = 0; }

    // ---- phase A: exact coarse pivot over 2048 bins (verbatim select0 math) ----
    unsigned int c0 = 0, c1 = 0;
    for (int p = 0; p < PARTS; ++p) {
        const unsigned int* hp = h0out + ((size_t)(b * PARTS + p)) * 2048;
        uint2 v = *(const uint2*)&hp[2 * tid];
        c0 += v.x; c1 += v.y;
    }
    unsigned int sum = c0 + c1;
#pragma unroll
    for (int off = 1; off < 64; off <<= 1) {
        unsigned int v = __shfl_down(sum, off, 64);
        if (lane + off < 64) sum += v;
    }
    if (lane == 0) wpart[wid] = sum;
    __syncthreads();
    if (tid < 16) {
        unsigned int e = 0;
        for (int w = tid + 1; w < 16; ++w) e += wpart[w];
        wexcl[tid] = e;
    }
    __syncthreads();
    unsigned int self = sum + wexcl[wid];    // count(bins >= 2*tid)
    thr[tid] = self;
    __syncthreads();
    unsigned int above = (tid < 1023) ? thr[tid + 1] : 0u;
    if (self >= (unsigned)PRE_K && above < (unsigned)PRE_K) {
        if (above + c1 >= (unsigned)PRE_K) {
            sh_piv = (unsigned)(2 * tid + 1); sh_need = (unsigned)(PRE_K)-above;
        } else {
            sh_piv = (unsigned)(2 * tid); sh_need = (unsigned)(PRE_K)-above - c1;
        }
    }
    __syncthreads();
    unsigned int piv = sh_piv;
    if (tid < PARTS && sbc[tid] > SLOT) sh_ok = 0;
    if (tid == 0 && piv < THR_BIN) sh_ok = 0;
    if (tid < 128) h128[tid] = 0;
    __syncthreads();
    int ok = sh_ok;

    // ---- phase B: 7-bit refinement hist ----
    if (ok) {
        for (int t = tid; t < PARTS * SLOT; t += 1024) {
            int p = t >> 9, off = t & (SLOT - 1);
            if (off < sbc[p]) {
                unsigned long long e = buf[((size_t)(b * PARTS + p)) * SLOT + off];
                unsigned int u = (unsigned int)(e >> 32);
                if ((u >> 21) == piv) atomicAdd(&h128[(u >> 14) & 127u], 1u);
            }
        }
    } else {
        // fallback (never taken for harness data): full resweep refine
        const float4* sp4 = (const float4*)(scores + (size_t)b * 18 * NCELL + (size_t)NA * NCELL);
        for (int t = tid; t < NTOT / 4; t += 1024) {
            float4 v = sp4[t];
            unsigned int u;
            u = sortable(v.x); if ((u >> 21) == piv) atomicAdd(&h128[(u >> 14) & 127u], 1u);
            u = sortable(v.y); if ((u >> 21) == piv) atomicAdd(&h128[(u >> 14) & 127u], 1u);
            u = sortable(v.z); if ((u >> 21) == piv) atomicAdd(&h128[(u >> 14) & 127u], 1u);
            u = sortable(v.w); if ((u >> 21) == piv) atomicAdd(&h128[(u >> 14) & 127u], 1u);
        }
    }
    __syncthreads();
    // exact 18-bit pivot (verbatim select1 math, wave 0)
    if (tid < 64) {
        unsigned int d0 = h128[2 * lane], d1 = h128[2 * lane + 1];
        unsigned int rs = d0 + d1;
#pragma unroll
        for (int off = 1; off < 64; off <<= 1) {
            unsigned int v = __shfl_down(rs, off, 64);
            if (lane + off < 64) rs += v;
        }
        unsigned int rab = __shfl_down(rs, 1, 64);
        if (lane == 63) rab = 0;
        unsigned int need0 = sh_need;
        if (rs >= need0 && rab < need0) {
            unsigned int d = (rab + d1 >= need0) ? (unsigned)(2 * lane + 1) : (unsigned)(2 * lane);
            sh_spiv = ((piv << 7) | d) << 14;
        }
    }
    __syncthreads();
    unsigned int spiv = sh_spiv;

    // ---- phase C: filter >= spiv into s[] ----
    if (ok) {
        for (int t = tid; t < PARTS * SLOT; t += 1024) {
            int p = t >> 9, off = t & (SLOT - 1);
            if (off < sbc[p]) {
                unsigned long long e = buf[((size_t)(b * PARTS + p)) * SLOT + off];
                if ((unsigned int)(e >> 32) >= spiv) {
                    int pos = atomicAdd(&fcnt, 1);
                    if (pos < 4096) s[pos] = e;
                }
            }
        }
    } else {
        const float4* sp4 = (const float4*)(scores + (size_t)b * 18 * NCELL + (size_t)NA * NCELL);
        for (int t4 = tid; t4 < NTOT / 4; t4 += 1024) {
            float4 v = sp4[t4];
            float el[4] = {v.x, v.y, v.z, v.w};
#pragma unroll
            for (int j = 0; j < 4; ++j) {
                unsigned int u = sortable(el[j]);
                if (u >= spiv) {
                    int idx4 = t4 * 4 + j;
                    int a = idx4 >> 14;
                    int cell = idx4 & 16383;
                    unsigned int i = (unsigned int)cell * 9u + (unsigned int)a;
                    int pos = atomicAdd(&fcnt, 1);
                    if (pos < 4096)
                        s[pos] = ((unsigned long long)u << 32) |
                                 (unsigned long long)(0xFFFFFFFFu - i);
                }
            }
        }
    }
    __syncthreads();
    int n2 = min(fcnt, 4096);
    int SZ = (n2 <= 2048) ? 2048 : 4096;
    for (int t = tid; t < SZ; t += 1024)
        if (t >= n2) s[t] = 0ULL;
    __syncthreads();

    // ---- phase D: sort (hybrid shuffle/LDS bitonic, verbatim) ----
    if (SZ == 2048) {
        unsigned long long va = s[2 * tid], vb = s[2 * tid + 1];
#pragma unroll
        for (unsigned k = 2; k <= 128; k <<= 1) {
#pragma unroll
            for (unsigned j = k >> 1; j >= 2; j >>= 1) SHFL_STEP(j)
            LOCAL_STEP()
        }
        for (unsigned k = 256; k <= 2048; k <<= 1) {
            s[2 * tid] = va; s[2 * tid + 1] = vb;
            __syncthreads();
            for (unsigned j = k >> 1; j >= 128; j >>= 1) {
                for (int t = tid; t < 2048; t += 1024) {
                    int ixj = t ^ (int)j;
                    if (ixj > t) {
                        unsigned long long x = s[t], y = s[ixj];
                        if ((((unsigned)t & k) == 0) ? (x < y) : (x > y)) { s[t] = y; s[ixj] = x; }
                    }
                }
                __syncthreads();
            }
            va = s[2 * tid]; vb = s[2 * tid + 1];
#pragma unroll
            for (unsigned j = 64; j >= 2; j >>= 1) SHFL_STEP(j)
            LOCAL_STEP()
        }
        s[2 * tid] = va; s[2 * tid + 1] = vb;
        __syncthreads();
    } else {
        for (int k = 2; k <= 4096; k <<= 1) {
            for (int j = k >> 1; j > 0; j >>= 1) {
                for (int t = tid; t < 4096; t += 1024) {
                    int ixj = t ^ j;
                    if (ixj > t) {
                        unsigned long long x = s[t], y = s[ixj];
                        if (((t & k) == 0) ? (x < y) : (x > y)) { s[t] = y; s[ixj] = x; }
                    }
                }
                __syncthreads();
            }
        }
    }

    // ---- phase E: decode + clip (numerics identical to passing version) ----
    float maxx = __fsub_rn(im_info[b * 3 + 1], 1.0f);
    float maxy = __fsub_rn(im_info[b * 3 + 0], 1.0f);
    const float* dbase = deltas + (size_t)b * 36 * NCELL;
    for (int r = tid; r < PRE_K; r += 1024) {
        unsigned int i = 0xFFFFFFFFu - (unsigned int)(s[r] & 0xFFFFFFFFu);
        unsigned int cell = i / 9u;
        unsigned int a = i - cell * 9u;
        int wx = (int)(cell & 127u), hy = (int)(cell >> 7);
        const float* dp = dbase + (size_t)(4u * a) * NCELL + (size_t)hy * 128 + wx;
        float dx = dp[0];
        float dy = dp[NCELL];
        float dw = dp[2 * NCELL];
        float dh = dp[3 * NCELL];
        float W_ = c_aw[a], H_ = c_ah[a];
        float cx = (float)(16 * wx + 8), cy = (float)(16 * hy + 8);
        float px = __fadd_rn(__fmul_rn(dx, W_), cx);
        float py = __fadd_rn(__fmul_rn(dy, H_), cy);
        float pw = __fmul_rn((float)exp((double)dw), W_);
        float ph = __fmul_rn((float)exp((double)dh), H_);
        float hw = __fmul_rn(0.5f, pw), hh = __fmul_rn(0.5f, ph);
        float x1 = __fsub_rn(px, hw), y1 = __fsub_rn(py, hh);
        float x2 = __fadd_rn(px, hw), y2 = __fadd_rn(py, hh);
        x1 = fminf(fmaxf(x1, 0.0f), maxx);
        y1 = fminf(fmaxf(y1, 0.0f), maxy);
        x2 = fminf(fmaxf(x2, 0.0f), maxx);
        y2 = fminf(fmaxf(y2, 0.0f), maxy);
        props[(size_t)b * PRE_K + r] = make_float4(x1, y1, x2, y2);
    }
}

// ---------------- NMS suppression bitmask, COLUMN form, word-major ----------------
// colm[(b*32 + iT)*2048 + j] : bit ii set iff box i=iT*64+ii suppresses box j (i<j, iou>th)
// grid (32 iTiles, 32 jTiles, B), block 64
__global__ void mask_kernel(const float4* __restrict__ boxes,
                            unsigned long long* __restrict__ colm) {
    int iT = blockIdx.x, jT = blockIdx.y, b = blockIdx.z;
    if (iT > jT) return;
    __shared__ float4 ib[64];
    int t = threadIdx.x;
    int i0 = iT * 64;
    ib[t] = (i0 + t < PRE_K) ? boxes[(size_t)b * PRE_K + i0 + t] : make_float4(0.f, 0.f, -1.f, -1.f);
    __syncthreads();
    int j = jT * 64 + t;
    if (j >= PRE_K) return;
    float4 jb = boxes[(size_t)b * PRE_K + j];
    float barea = __fmul_rn(__fsub_rn(jb.z, jb.x), __fsub_rn(jb.w, jb.y));
    unsigned long long m = 0ULL;
    for (int ii = 0; ii < 64; ++ii) {
        int i = i0 + ii;
        if (i < j) {   // i < j < PRE_K
            float4 c = ib[ii];
            float aarea = __fmul_rn(__fsub_rn(c.z, c.x), __fsub_rn(c.w, c.y));
            float xx1 = fmaxf(c.x, jb.x), yy1 = fmaxf(c.y, jb.y);
            float xx2 = fminf(c.z, jb.z), yy2 = fminf(c.w, jb.w);
            float iw = fmaxf(__fsub_rn(xx2, xx1), 0.0f);
            float ih = fmaxf(__fsub_rn(yy2, yy1), 0.0f);
            float inter = __fmul_rn(iw, ih);
            float denom = __fadd_rn(__fsub_rn(__fadd_rn(aarea, barea), inter), 1e-9f);
            float iou = __fdiv_rn(inter, denom);
            if (iou > NMS_TH) m |= (1ULL << ii);
        }
    }
    colm[((size_t)b * 32 + iT) * 2048 + j] = m;
}

// ---------------- greedy scan via ballots, one wave per batch (ILP-8 dead-check) ----------------
__global__ void scan_kernel(const unsigned long long* __restrict__ colm,
                            const float4* __restrict__ boxes,
                            float* __restrict__ out) {
    int b = blockIdx.x;
    int lane = threadIdx.x;  // 64 threads = 1 wave
    __shared__ unsigned long long kw[32];
    __shared__ int keeplist[POST_K];
    const unsigned long long* cb = colm + (size_t)b * 32 * 2048;
    int total = 0;
    bool done = false;
    for (int k = 0; k < 32 && !done; ++k) {
        int j = k * 64 + lane;
        unsigned long long d = 0;
        int w = 0;
        for (; w + 8 <= k; w += 8) {
            unsigned long long a0 = cb[(size_t)(w + 0) * 2048 + j] & kw[w + 0];
            unsigned long long a1 = cb[(size_t)(w + 1) * 2048 + j] & kw[w + 1];
            unsigned long long a2 = cb[(size_t)(w + 2) * 2048 + j] & kw[w + 2];
            unsigned long long a3 = cb[(size_t)(w + 3) * 2048 + j] & kw[w + 3];
            unsigned long long a4 = cb[(size_t)(w + 4) * 2048 + j] & kw[w + 4];
            unsigned long long a5 = cb[(size_t)(w + 5) * 2048 + j] & kw[w + 5];
            unsigned long long a6 = cb[(size_t)(w + 6) * 2048 + j] & kw[w + 6];
            unsigned long long a7 = cb[(size_t)(w + 7) * 2048 + j] & kw[w + 7];
            d |= ((a0 | a1) | (a2 | a3)) | ((a4 | a5) | (a6 | a7));
        }
        for (; w < k; ++w) d |= cb[(size_t)w * 2048 + j] & kw[w];
        unsigned long long diag = cb[(size_t)k * 2048 + j];
        bool alive_me = (d == 0ULL) && (j < PRE_K);
        unsigned long long alive = __ballot(alive_me);
        unsigned long long keptw = 0ULL;
        while (alive) {
            int i = __builtin_ctzll(alive);
            keptw |= (1ULL << i);
            if (lane == 0 && total < POST_K) keeplist[total] = k * 64 + i;
            total++;
            if (total >= POST_K) { done = true; break; }
            unsigned long long sup = __ballot(((diag >> i) & 1ULL) != 0ULL);
            alive &= ~sup;
            alive &= ~keptw;
        }
        if (lane == 0) kw[k] = keptw;
        __syncthreads();
    }
    __syncthreads();
    int K = min(total, POST_K);
    const float4* bb = boxes + (size_t)b * PRE_K;
    for (int r = lane; r < POST_K; r += 64) {
        float4 v = make_float4(0.f, 0.f, 0.f, 0.f);
        if (r < K) v = bb[keeplist[r]];
        float* o = out + ((size_t)b * POST_K + r) * 5;
        o[0] = (float)b;
        o[1] = v.x;
        o[2] = v.y;
        o[3] = v.z;
        o[4] = v.w;
    }
}

// ---------------- launcher ----------------
extern "C" void kernel_launch(void* const* d_in, const int* in_sizes, int n_in,
                              void* d_out, int out_size, void* d_ws, size_t ws_size,
                              hipStream_t stream) {
    const float* scores = (const float*)d_in[0];
    const float* deltas = (const float*)d_in[1];
    const float* im_info = (const float*)d_in[2];
    float* out = (float*)d_out;
    char* ws = (char*)d_ws;

    // workspace layout (bytes); every consumed byte is written earlier in the same call
    unsigned int* h0out = (unsigned int*)(ws + 0);                 // 144*2048*4 = 1179648
    int* bcnt = (int*)(ws + 1179648);                              // 144*4 = 576 (pad 1024)
    unsigned long long* buf = (unsigned long long*)(ws + 1180672); // 144*512*8 = 589824
    float4* props = (float4*)(ws + 1770496);                       // 8*2000*16 = 256000
    unsigned long long* colm = (unsigned long long*)(ws + 2026496);// 8*32*2048*8 = 4194304
    // total ≈ 6.22 MB

    hipLaunchKernelGGL(sweep_kernel, dim3(PARTS, NB), dim3(1024), 0, stream,
                       scores, h0out, bcnt, buf);
    hipLaunchKernelGGL(sortdec_kernel, dim3(NB), dim3(1024), 0, stream,
                       scores, h0out, bcnt, buf, deltas, im_info, props);
    hipLaunchKernelGGL(mask_kernel, dim3(32, 32, NB), dim3(64), 0, stream, props, colm);
    hipLaunchKernelGGL(scan_kernel, dim3(NB), dim3(64), 0, stream, colm, props, out);
}

// Round 10
// 100.087 us; speedup vs baseline: 1.0320x; 1.0217x over previous
//
#include <hip/hip_runtime.h>

#define NB 8
#define NA 9
#define NCELL (128 * 128)    // 16384
#define NTOT (NCELL * NA)    // 147456
#define PRE_K 2000
#define POST_K 300
#define PARTS 18             // sweep blocks per batch (1024 thr, 8192 elems each)
#define SLOT 512             // candidate slots per sweep block
#define THR_BIN 0x5FFu       // static gather bin: sortable(1.75f)>>21
#define NMS_TH 0.7f

// anchor widths/heights (exact integers); all anchor centers are 16*(w,h)+8
__constant__ float c_aw[NA] = {184.f, 368.f, 736.f, 128.f, 256.f, 512.f, 88.f, 176.f, 352.f};
__constant__ float c_ah[NA] = {96.f, 192.f, 384.f, 128.f, 256.f, 512.f, 176.f, 352.f, 704.f};

__device__ __forceinline__ unsigned int sortable(float s) {
    unsigned int u = __float_as_uint(s);
    return (u & 0x80000000u) ? ~u : (u | 0x80000000u);
}

__device__ __forceinline__ unsigned long long shflx64(unsigned long long v, int m) {
    return __shfl_xor(v, m, 64);
}

// ---------- single sweep: 2048-bin hist + static-threshold gather into slots ----------
// grid (PARTS, NB) x 1024; block covers 2048 float4 = 8192 elems
__global__ __launch_bounds__(1024) void sweep_kernel(const float* __restrict__ scores,
                                                     unsigned int* __restrict__ h0out,
                                                     int* __restrict__ bcnt,
                                                     unsigned long long* __restrict__ buf) {
    __shared__ unsigned int h[2048];
    __shared__ unsigned long long lbuf[SLOT];
    __shared__ int lcnt;
    int b = blockIdx.y, part = blockIdx.x, tid = threadIdx.x;
    h[tid] = 0; h[tid + 1024] = 0;
    if (tid == 0) lcnt = 0;
    __syncthreads();
    const float4* sp4 = (const float4*)(scores + (size_t)b * 18 * NCELL + (size_t)NA * NCELL);
    int base4 = part * 2048;
#pragma unroll
    for (int e = 0; e < 2; ++e) {
        int t4 = base4 + e * 1024 + tid;
        float4 v = sp4[t4];
        float el[4] = {v.x, v.y, v.z, v.w};
#pragma unroll
        for (int j = 0; j < 4; ++j) {
            unsigned int u = sortable(el[j]);
            atomicAdd(&h[u >> 21], 1u);
            if ((u >> 21) >= THR_BIN) {
                int idx4 = t4 * 4 + j;            // = a*16384 + cell (channel-major)
                int a = idx4 >> 14;
                int cell = idx4 & 16383;
                unsigned int i = (unsigned int)cell * 9u + (unsigned int)a;
                int pos = atomicAdd(&lcnt, 1);
                if (pos < SLOT)
                    lbuf[pos] = ((unsigned long long)u << 32) |
                                (unsigned long long)(0xFFFFFFFFu - i);
            }
        }
    }
    __syncthreads();
    unsigned int* o = h0out + ((size_t)(b * PARTS + part)) * 2048;
    o[tid] = h[tid];
    o[tid + 1024] = h[tid + 1024];
    if (tid == 0) bcnt[b * PARTS + part] = lcnt;   // raw count (may exceed SLOT)
    int m = min(lcnt, SLOT);
    for (int t = tid; t < m; t += 1024)
        buf[((size_t)(b * PARTS + part)) * SLOT + t] = lbuf[t];
}

// ---------- per-batch: coarse select + refine + filter + hybrid sort -> topidx ----------
#define SHFL_STEP(J)                                                          \
    {                                                                         \
        int d_ = (J) >> 1;                                                    \
        bool keepMax = (((tid & d_) == 0) == (((2u * (unsigned)tid) & k) == 0)); \
        unsigned long long pa = shflx64(va, d_);                              \
        unsigned long long pb = shflx64(vb, d_);                              \
        va = keepMax ? (va > pa ? va : pa) : (va < pa ? va : pa);             \
        vb = keepMax ? (vb > pb ? vb : pb) : (vb < pb ? vb : pb);             \
    }
#define LOCAL_STEP()                                                          \
    {                                                                         \
        bool desc = (((2u * (unsigned)tid) & k) == 0);                        \
        unsigned long long lo = va < vb ? va : vb;                            \
        unsigned long long hi = va < vb ? vb : va;                            \
        va = desc ? hi : lo; vb = desc ? lo : hi;                             \
    }

__global__ __launch_bounds__(1024) void sortdec_kernel(const float* __restrict__ scores,
                                                       const unsigned int* __restrict__ h0out,
                                                       const int* __restrict__ bcnt,
                                                       const unsigned long long* __restrict__ buf,
                                                       unsigned int* __restrict__ topidx) {
    __shared__ unsigned long long s[4096];        // 32 KB; aliased as thr[] in phase A
    __shared__ unsigned int wpart[16], wexcl[16];
    __shared__ unsigned int h128[128];
    __shared__ int sbc[PARTS];
    __shared__ unsigned int sh_piv, sh_spiv;
    __shared__ unsigned int sh_need;
    __shared__ int sh_ok, fcnt;
    int b = blockIdx.x, tid = threadIdx.x;
    int lane = tid & 63, wid = tid >> 6;
    unsigned int* thr = (unsigned int*)s;   // phase-A only

    if (tid < PARTS) sbc[tid] = bcnt[b * PARTS + tid];
    if (tid == 0) { sh_ok = 1; fcnt = 0; }

    // ---- phase A: exact coarse pivot over 2048 bins ----
    unsigned int c0 = 0, c1 = 0;
#pragma unroll
    for (int p = 0; p < PARTS; ++p) {
        const unsigned int* hp = h0out + ((size_t)(b * PARTS + p)) * 2048;
        uint2 v = *(const uint2*)&hp[2 * tid];
        c0 += v.x; c1 += v.y;
    }
    unsigned int sum = c0 + c1;
#pragma unroll
    for (int off = 1; off < 64; off <<= 1) {
        unsigned int v = __shfl_down(sum, off, 64);
        if (lane + off < 64) sum += v;
    }
    if (lane == 0) wpart[wid] = sum;
    __syncthreads();
    if (tid < 16) {
        unsigned int e = 0;
        for (int w = tid + 1; w < 16; ++w) e += wpart[w];
        wexcl[tid] = e;
    }
    __syncthreads();
    unsigned int self = sum + wexcl[wid];    // count(bins >= 2*tid)
    thr[tid] = self;
    __syncthreads();
    unsigned int above = (tid < 1023) ? thr[tid + 1] : 0u;
    if (self >= (unsigned)PRE_K && above < (unsigned)PRE_K) {
        if (above + c1 >= (unsigned)PRE_K) {
            sh_piv = (unsigned)(2 * tid + 1); sh_need = (unsigned)(PRE_K)-above;
        } else {
            sh_piv = (unsigned)(2 * tid); sh_need = (unsigned)(PRE_K)-above - c1;
        }
    }
    __syncthreads();
    unsigned int piv = sh_piv;
    if (tid < PARTS && sbc[tid] > SLOT) sh_ok = 0;
    if (tid == 0 && piv < THR_BIN) sh_ok = 0;
    if (tid < 128) h128[tid] = 0;
    __syncthreads();
    int ok = sh_ok;

    // ---- phase B: 7-bit refinement hist ----
    if (ok) {
        for (int t = tid; t < PARTS * SLOT; t += 1024) {
            int p = t >> 9, off = t & (SLOT - 1);
            if (off < sbc[p]) {
                unsigned long long e = buf[((size_t)(b * PARTS + p)) * SLOT + off];
                unsigned int u = (unsigned int)(e >> 32);
                if ((u >> 21) == piv) atomicAdd(&h128[(u >> 14) & 127u], 1u);
            }
        }
    } else {
        // fallback (never taken for harness data): full resweep refine
        const float4* sp4 = (const float4*)(scores + (size_t)b * 18 * NCELL + (size_t)NA * NCELL);
        for (int t = tid; t < NTOT / 4; t += 1024) {
            float4 v = sp4[t];
            unsigned int u;
            u = sortable(v.x); if ((u >> 21) == piv) atomicAdd(&h128[(u >> 14) & 127u], 1u);
            u = sortable(v.y); if ((u >> 21) == piv) atomicAdd(&h128[(u >> 14) & 127u], 1u);
            u = sortable(v.z); if ((u >> 21) == piv) atomicAdd(&h128[(u >> 14) & 127u], 1u);
            u = sortable(v.w); if ((u >> 21) == piv) atomicAdd(&h128[(u >> 14) & 127u], 1u);
        }
    }
    __syncthreads();
    // exact 18-bit pivot (wave 0)
    if (tid < 64) {
        unsigned int d0 = h128[2 * lane], d1 = h128[2 * lane + 1];
        unsigned int rs = d0 + d1;
#pragma unroll
        for (int off = 1; off < 64; off <<= 1) {
            unsigned int v = __shfl_down(rs, off, 64);
            if (lane + off < 64) rs += v;
        }
        unsigned int rab = __shfl_down(rs, 1, 64);
        if (lane == 63) rab = 0;
        unsigned int need0 = sh_need;
        if (rs >= need0 && rab < need0) {
            unsigned int d = (rab + d1 >= need0) ? (unsigned)(2 * lane + 1) : (unsigned)(2 * lane);
            sh_spiv = ((piv << 7) | d) << 14;
        }
    }
    __syncthreads();
    unsigned int spiv = sh_spiv;

    // ---- phase C: filter >= spiv into s[] ----
    if (ok) {
        for (int t = tid; t < PARTS * SLOT; t += 1024) {
            int p = t >> 9, off = t & (SLOT - 1);
            if (off < sbc[p]) {
                unsigned long long e = buf[((size_t)(b * PARTS + p)) * SLOT + off];
                if ((unsigned int)(e >> 32) >= spiv) {
                    int pos = atomicAdd(&fcnt, 1);
                    if (pos < 4096) s[pos] = e;
                }
            }
        }
    } else {
        const float4* sp4 = (const float4*)(scores + (size_t)b * 18 * NCELL + (size_t)NA * NCELL);
        for (int t4 = tid; t4 < NTOT / 4; t4 += 1024) {
            float4 v = sp4[t4];
            float el[4] = {v.x, v.y, v.z, v.w};
#pragma unroll
            for (int j = 0; j < 4; ++j) {
                unsigned int u = sortable(el[j]);
                if (u >= spiv) {
                    int idx4 = t4 * 4 + j;
                    int a = idx4 >> 14;
                    int cell = idx4 & 16383;
                    unsigned int i = (unsigned int)cell * 9u + (unsigned int)a;
                    int pos = atomicAdd(&fcnt, 1);
                    if (pos < 4096)
                        s[pos] = ((unsigned long long)u << 32) |
                                 (unsigned long long)(0xFFFFFFFFu - i);
                }
            }
        }
    }
    __syncthreads();
    int n2 = min(fcnt, 4096);
    int SZ = (n2 <= 2048) ? 2048 : 4096;
    for (int t = tid; t < SZ; t += 1024)
        if (t >= n2) s[t] = 0ULL;
    __syncthreads();

    // ---- phase D: sort (hybrid shuffle/LDS bitonic, verbatim) ----
    if (SZ == 2048) {
        unsigned long long va = s[2 * tid], vb = s[2 * tid + 1];
#pragma unroll
        for (unsigned k = 2; k <= 128; k <<= 1) {
#pragma unroll
            for (unsigned j = k >> 1; j >= 2; j >>= 1) SHFL_STEP(j)
            LOCAL_STEP()
        }
        for (unsigned k = 256; k <= 2048; k <<= 1) {
            s[2 * tid] = va; s[2 * tid + 1] = vb;
            __syncthreads();
            for (unsigned j = k >> 1; j >= 128; j >>= 1) {
                for (int t = tid; t < 2048; t += 1024) {
                    int ixj = t ^ (int)j;
                    if (ixj > t) {
                        unsigned long long x = s[t], y = s[ixj];
                        if ((((unsigned)t & k) == 0) ? (x < y) : (x > y)) { s[t] = y; s[ixj] = x; }
                    }
                }
                __syncthreads();
            }
            va = s[2 * tid]; vb = s[2 * tid + 1];
#pragma unroll
            for (unsigned j = 64; j >= 2; j >>= 1) SHFL_STEP(j)
            LOCAL_STEP()
        }
        s[2 * tid] = va; s[2 * tid + 1] = vb;
        __syncthreads();
    } else {
        for (int k = 2; k <= 4096; k <<= 1) {
            for (int j = k >> 1; j > 0; j >>= 1) {
                for (int t = tid; t < 4096; t += 1024) {
                    int ixj = t ^ j;
                    if (ixj > t) {
                        unsigned long long x = s[t], y = s[ixj];
                        if (((t & k) == 0) ? (x < y) : (x > y)) { s[t] = y; s[ixj] = x; }
                    }
                }
                __syncthreads();
            }
        }
    }
    for (int r = tid; r < PRE_K; r += 1024)
        topidx[(size_t)b * PRE_K + r] = 0xFFFFFFFFu - (unsigned int)(s[r] & 0xFFFFFFFFu);
}

// ---------- decode + clip boxes, chip-wide (verbatim R4, absmax=0 proven) ----------
__global__ void decode_kernel(const unsigned int* __restrict__ topidx,
                              const float* __restrict__ deltas,
                              const float* __restrict__ im_info,
                              float4* __restrict__ props) {
    int gid = blockIdx.x * 256 + threadIdx.x;
    if (gid >= NB * PRE_K) return;
    int b = gid / PRE_K;
    unsigned int i = topidx[gid];
    unsigned int cell = i / 9u;
    unsigned int a = i - cell * 9u;
    int wx = (int)(cell & 127u), hy = (int)(cell >> 7);
    const float* dp = deltas + (size_t)b * 36 * NCELL + (size_t)(4u * a) * NCELL +
                      (size_t)hy * 128 + wx;
    float dx = dp[0];
    float dy = dp[NCELL];
    float dw = dp[2 * NCELL];
    float dh = dp[3 * NCELL];
    float W_ = c_aw[a], H_ = c_ah[a];
    float cx = (float)(16 * wx + 8), cy = (float)(16 * hy + 8);
    float px = __fadd_rn(__fmul_rn(dx, W_), cx);
    float py = __fadd_rn(__fmul_rn(dy, H_), cy);
    float pw = __fmul_rn((float)exp((double)dw), W_);
    float ph = __fmul_rn((float)exp((double)dh), H_);
    float hw = __fmul_rn(0.5f, pw), hh = __fmul_rn(0.5f, ph);
    float x1 = __fsub_rn(px, hw), y1 = __fsub_rn(py, hh);
    float x2 = __fadd_rn(px, hw), y2 = __fadd_rn(py, hh);
    float maxx = __fsub_rn(im_info[b * 3 + 1], 1.0f);
    float maxy = __fsub_rn(im_info[b * 3 + 0], 1.0f);
    x1 = fminf(fmaxf(x1, 0.0f), maxx);
    y1 = fminf(fmaxf(y1, 0.0f), maxy);
    x2 = fminf(fmaxf(x2, 0.0f), maxx);
    y2 = fminf(fmaxf(y2, 0.0f), maxy);
    props[gid] = make_float4(x1, y1, x2, y2);
}

// ---------------- NMS suppression bitmask, COLUMN form, word-major ----------------
// colm[(b*32 + iT)*2048 + j] : bit ii set iff box i=iT*64+ii suppresses box j (i<j, iou>th)
// grid (32 iTiles, 32 jTiles, B), block 64
__global__ void mask_kernel(const float4* __restrict__ boxes,
                            unsigned long long* __restrict__ colm) {
    int iT = blockIdx.x, jT = blockIdx.y, b = blockIdx.z;
    if (iT > jT) return;
    __shared__ float4 ib[64];
    int t = threadIdx.x;
    int i0 = iT * 64;
    ib[t] = (i0 + t < PRE_K) ? boxes[(size_t)b * PRE_K + i0 + t] : make_float4(0.f, 0.f, -1.f, -1.f);
    __syncthreads();
    int j = jT * 64 + t;
    if (j >= PRE_K) return;
    float4 jb = boxes[(size_t)b * PRE_K + j];
    float barea = __fmul_rn(__fsub_rn(jb.z, jb.x), __fsub_rn(jb.w, jb.y));
    unsigned long long m = 0ULL;
    for (int ii = 0; ii < 64; ++ii) {
        int i = i0 + ii;
        if (i < j) {   // i < j < PRE_K
            float4 c = ib[ii];
            float aarea = __fmul_rn(__fsub_rn(c.z, c.x), __fsub_rn(c.w, c.y));
            float xx1 = fmaxf(c.x, jb.x), yy1 = fmaxf(c.y, jb.y);
            float xx2 = fminf(c.z, jb.z), yy2 = fminf(c.w, jb.w);
            float iw = fmaxf(__fsub_rn(xx2, xx1), 0.0f);
            float ih = fmaxf(__fsub_rn(yy2, yy1), 0.0f);
            float inter = __fmul_rn(iw, ih);
            float denom = __fadd_rn(__fsub_rn(__fadd_rn(aarea, barea), inter), 1e-9f);
            float iou = __fdiv_rn(inter, denom);
            if (iou > NMS_TH) m |= (1ULL << ii);
        }
    }
    colm[((size_t)b * 32 + iT) * 2048 + j] = m;
}

// ---------------- greedy scan v2: incremental dead flags, 16 waves, prefetch ----------------
__global__ __launch_bounds__(1024) void scan_kernel(const unsigned long long* __restrict__ colm,
                                                    const float4* __restrict__ boxes,
                                                    float* __restrict__ out) {
    __shared__ int keeplist[POST_K];
    __shared__ unsigned long long kw_sh;
    __shared__ int ctl[2];   // [0]=total [1]=done
    int b = blockIdx.x, tid = threadIdx.x;
    int lane = tid & 63, wid = tid >> 6;           // 16 waves
    int t0 = wid, t1 = wid + 16;                   // tiles owned by this wave
    const unsigned long long* cb = colm + (size_t)b * 32 * 2048;
    if (tid == 0) { ctl[0] = 0; ctl[1] = 0; }
    int d0 = 0, d1 = 0;                            // dead flags for lane's box in t0 / t1
    // prefetch diagonal words and first update rows
    unsigned long long diag0 = cb[(size_t)t0 * 2048 + t0 * 64 + lane];
    unsigned long long diag1 = cb[(size_t)t1 * 2048 + t1 * 64 + lane];
    unsigned long long w0 = (t0 > 0) ? cb[t0 * 64 + lane] : 0ULL;     // colm[0][t0*64+lane]
    unsigned long long w1 = cb[t1 * 64 + lane];                       // colm[0][t1*64+lane]
    __syncthreads();
    for (int k = 0; k < 32; ++k) {
        if (wid == (k & 15)) {
            // this wave owns tile k (as t0 if k<16 else t1): greedy (verbatim inner loop)
            bool isT1 = (k >= 16);
            int j = k * 64 + lane;
            unsigned long long diag = isT1 ? diag1 : diag0;
            bool alive_me = ((isT1 ? d1 : d0) == 0) && (j < PRE_K);
            unsigned long long alive = __ballot(alive_me);
            unsigned long long keptw = 0ULL;
            int total = ctl[0];
            int done = 0;
            while (alive) {
                int i = __builtin_ctzll(alive);
                keptw |= (1ULL << i);
                if (lane == 0 && total < POST_K) keeplist[total] = k * 64 + i;
                total++;
                if (total >= POST_K) { done = 1; break; }
                unsigned long long sup = __ballot(((diag >> i) & 1ULL) != 0ULL);
                alive &= ~sup;
                alive &= ~keptw;
            }
            if (lane == 0) { ctl[0] = total; ctl[1] = done; kw_sh = keptw; }
        }
        __syncthreads();
        if (ctl[1]) break;
        unsigned long long kwk = kw_sh;
        // consume prefetched rows for step k, then prefetch step k+1
        if (t0 > k && (w0 & kwk)) d0 = 1;
        if (t1 > k && (w1 & kwk)) d1 = 1;
        if (k + 1 < 32) {
            if (t0 > k + 1) w0 = cb[(size_t)(k + 1) * 2048 + t0 * 64 + lane];
            if (t1 > k + 1) w1 = cb[(size_t)(k + 1) * 2048 + t1 * 64 + lane];
        }
        __syncthreads();
    }
    __syncthreads();
    int K = min(ctl[0], POST_K);
    const float4* bb = boxes + (size_t)b * PRE_K;
    for (int r = tid; r < POST_K; r += 1024) {
        float4 v = make_float4(0.f, 0.f, 0.f, 0.f);
        if (r < K) v = bb[keeplist[r]];
        float* o = out + ((size_t)b * POST_K + r) * 5;
        o[0] = (float)b;
        o[1] = v.x;
        o[2] = v.y;
        o[3] = v.z;
        o[4] = v.w;
    }
}

// ---------------- launcher ----------------
extern "C" void kernel_launch(void* const* d_in, const int* in_sizes, int n_in,
                              void* d_out, int out_size, void* d_ws, size_t ws_size,
                              hipStream_t stream) {
    const float* scores = (const float*)d_in[0];
    const float* deltas = (const float*)d_in[1];
    const float* im_info = (const float*)d_in[2];
    float* out = (float*)d_out;
    char* ws = (char*)d_ws;

    // workspace layout (bytes); every consumed byte is written earlier in the same call
    unsigned int* h0out = (unsigned int*)(ws + 0);                 // 144*2048*4 = 1179648
    int* bcnt = (int*)(ws + 1179648);                              // 576 (pad to 1024)
    unsigned long long* buf = (unsigned long long*)(ws + 1180672); // 144*512*8 = 589824
    unsigned int* topidx = (unsigned int*)(ws + 1770496);          // 8*2000*4 = 64000
    float4* props = (float4*)(ws + 1834496);                       // 8*2000*16 = 256000
    unsigned long long* colm = (unsigned long long*)(ws + 2090496);// 8*32*2048*8 = 4194304
    // total ≈ 6.28 MB

    hipLaunchKernelGGL(sweep_kernel, dim3(PARTS, NB), dim3(1024), 0, stream,
                       scores, h0out, bcnt, buf);
    hipLaunchKernelGGL(sortdec_kernel, dim3(NB), dim3(1024), 0, stream,
                       scores, h0out, bcnt, buf, topidx);
    hipLaunchKernelGGL(decode_kernel, dim3((NB * PRE_K + 255) / 256), dim3(256), 0, stream,
                       topidx, deltas, im_info, props);
    hipLaunchKernelGGL(mask_kernel, dim3(32, 32, NB), dim3(64), 0, stream, props, colm);
    hipLaunchKernelGGL(scan_kernel, dim3(NB), dim3(1024), 0, stream, colm, props, out);
}